// Round 1
// baseline (179.716 us; speedup 1.0000x reference)
//
#include <hip/hip_runtime.h>
#include <hip/hip_bf16.h>

#define N_ROWS 8192
#define DIM    128
#define TWO_N  16384
#define CSPLIT 8
#define COLS_PER_BLOCK (TWO_N / CSPLIT)   // 2048
#define CT 32                             // cols per LDS tile
#define NT (COLS_PER_BLOCK / CT)          // 64 tiles
#define EXP_TWO 7.38905609893065f

typedef __attribute__((ext_vector_type(8))) short short8;
typedef __attribute__((ext_vector_type(4))) float float4v;

__device__ inline void async_copy16(const void* g, void* l) {
  __builtin_amdgcn_global_load_lds(
      (const __attribute__((address_space(1))) void*)g,
      (__attribute__((address_space(3))) void*)l, 16, 0, 0);
}

// ---------------------------------------------------------------------------
// Kernel 1: L2-normalize rows of h1,h2 (fp32), write bf16 H = [h1n; h2n],
// write exact fp32 pos-dot per row (no atomics).
// One wave per row; block = 4 waves.
// ---------------------------------------------------------------------------
__global__ __launch_bounds__(256) void norm_kernel(
    const float* __restrict__ h1, const float* __restrict__ h2,
    __hip_bfloat16* __restrict__ Hb, float* __restrict__ posdot) {
  int lane = threadIdx.x & 63;
  int w    = threadIdx.x >> 6;
  int row  = blockIdx.x * 4 + w;                  // 0..8191

  const float2* p1 = (const float2*)(h1 + (size_t)row * DIM);
  const float2* p2 = (const float2*)(h2 + (size_t)row * DIM);
  float2 v1 = p1[lane];
  float2 v2 = p2[lane];

  float ss1 = v1.x * v1.x + v1.y * v1.y;
  float ss2 = v2.x * v2.x + v2.y * v2.y;
  #pragma unroll
  for (int m = 32; m; m >>= 1) {
    ss1 += __shfl_xor(ss1, m);
    ss2 += __shfl_xor(ss2, m);
  }
  float inv1 = 1.0f / fmaxf(sqrtf(ss1), 1e-12f);
  float inv2 = 1.0f / fmaxf(sqrtf(ss2), 1e-12f);

  float ax = v1.x * inv1, ay = v1.y * inv1;
  float bx = v2.x * inv2, by = v2.y * inv2;

  float pd = ax * bx + ay * by;
  #pragma unroll
  for (int m = 32; m; m >>= 1) pd += __shfl_xor(pd, m);

  __hip_bfloat162* o1 = (__hip_bfloat162*)(Hb + (size_t)row * DIM);
  __hip_bfloat162* o2 = (__hip_bfloat162*)(Hb + (size_t)(row + N_ROWS) * DIM);
  __hip_bfloat162 t1, t2;
  t1.x = __float2bfloat16(ax); t1.y = __float2bfloat16(ay);
  t2.x = __float2bfloat16(bx); t2.y = __float2bfloat16(by);
  o1[lane] = t1;
  o2[lane] = t2;

  if (lane == 0) posdot[row] = pd;
}

// ---------------------------------------------------------------------------
// Kernel 2: row sums of exp(2 * H H^T) without materializing the matrix.
// Block: 256 threads = 4 waves; each wave owns 64 rows (A in registers,
// K=128 entirely resident). B tiles (32 cols x 128 k) staged to LDS via
// global_load_lds in MFMA fragment order (chunk i -> c=i>>8, s=(i>>6)&3,
// lane=i&63), so ds_read_b128 is lane-sequential (conflict-free).
// Grid: (64 row-stripes, 8 col-splits). Partial row sums via atomicAdd.
// ---------------------------------------------------------------------------
__global__ __launch_bounds__(256, 2) void ntx_main(
    const __hip_bfloat16* __restrict__ Hb, float* __restrict__ rowsum) {
  __shared__ short smem[512 * 8];   // 8 KB: 512 chunks of 16 B
  const short* H = (const short*)Hb;

  int tid  = threadIdx.x;
  int lane = tid & 63;
  int w    = tid >> 6;
  int q    = lane >> 4;     // k-chunk selector within fragment
  int m    = lane & 15;     // row-within-subtile / col-within-subtile

  int rowbase = blockIdx.x * 256 + w * 64;
  int colbase = blockIdx.y * COLS_PER_BLOCK;

  // A fragments: 4 row-subtiles x 4 k-steps, held for the whole kernel.
  short8 a[4][4];
  #pragma unroll
  for (int r = 0; r < 4; ++r)
    #pragma unroll
    for (int s = 0; s < 4; ++s)
      a[r][s] = *(const short8*)(H + (size_t)(rowbase + r * 16 + m) * DIM + s * 32 + q * 8);

  float rowacc[4][4];
  #pragma unroll
  for (int r = 0; r < 4; ++r)
    #pragma unroll
    for (int i = 0; i < 4; ++i) rowacc[r][i] = 0.0f;

  for (int ct = 0; ct < NT; ++ct) {
    int j0 = colbase + ct * CT;
    // Stage B tile (32 rows of H x 128 k) in fragment order.
    #pragma unroll
    for (int rr = 0; rr < 2; ++rr) {
      int i   = rr * 256 + tid;          // chunk index 0..511
      int c   = i >> 8;                  // col-subtile
      int s   = (i >> 6) & 3;            // k-step
      int l15 = i & 15;                  // lane&15 -> B row within subtile
      int lq  = (i >> 4) & 3;            // lane>>4 -> k chunk
      const short* g = H + (size_t)(j0 + c * 16 + l15) * DIM + s * 32 + lq * 8;
      async_copy16(g, (void*)&smem[i * 8]);
    }
    __syncthreads();   // compiler emits s_waitcnt vmcnt(0) before s_barrier

    #pragma unroll
    for (int c = 0; c < 2; ++c) {
      short8 b[4];
      #pragma unroll
      for (int s = 0; s < 4; ++s)
        b[s] = *(const short8*)&smem[(c * 256 + s * 64 + lane) * 8];
      #pragma unroll
      for (int r = 0; r < 4; ++r) {
        float4v acc = {0.f, 0.f, 0.f, 0.f};
        #pragma unroll
        for (int s = 0; s < 4; ++s)
          acc = __builtin_amdgcn_mfma_f32_16x16x32_bf16(a[r][s], b[s], acc, 0, 0, 0);
        #pragma unroll
        for (int i = 0; i < 4; ++i)
          rowacc[r][i] += __expf(2.0f * acc[i]);
      }
    }
    __syncthreads();
  }

  // Reduce across the 16 column-lanes (lane&15) holding the same rows.
  #pragma unroll
  for (int r = 0; r < 4; ++r)
    #pragma unroll
    for (int i = 0; i < 4; ++i) {
      float v = rowacc[r][i];
      v += __shfl_xor(v, 1);
      v += __shfl_xor(v, 2);
      v += __shfl_xor(v, 4);
      v += __shfl_xor(v, 8);
      rowacc[r][i] = v;
    }
  if (m == 0) {
    #pragma unroll
    for (int r = 0; r < 4; ++r)
      #pragma unroll
      for (int i = 0; i < 4; ++i)
        atomicAdd(&rowsum[rowbase + r * 16 + q * 4 + i], rowacc[r][i]);
  }
}

// ---------------------------------------------------------------------------
// Kernel 3: loss = ( sum_i log(rowsum_i - e^2) - 4 * sum_i posdot_i ) / 2N
// ---------------------------------------------------------------------------
__global__ __launch_bounds__(256) void finalize(
    const float* __restrict__ rowsum, const float* __restrict__ posdot,
    float* __restrict__ out) {
  __shared__ float red[8];
  int tid = threadIdx.x;
  float ld = 0.0f, pp = 0.0f;
  for (int i = tid; i < TWO_N; i += 256) ld += logf(rowsum[i] - EXP_TWO);
  for (int i = tid; i < N_ROWS; i += 256) pp += posdot[i];
  #pragma unroll
  for (int m = 32; m; m >>= 1) {
    ld += __shfl_xor(ld, m);
    pp += __shfl_xor(pp, m);
  }
  if ((tid & 63) == 0) {
    red[tid >> 6] = ld;
    red[4 + (tid >> 6)] = pp;
  }
  __syncthreads();
  if (tid == 0) {
    float tl = red[0] + red[1] + red[2] + red[3];
    float tp = red[4] + red[5] + red[6] + red[7];
    *out = (tl - 4.0f * tp) / (float)TWO_N;
  }
}

extern "C" void kernel_launch(void* const* d_in, const int* in_sizes, int n_in,
                              void* d_out, int out_size, void* d_ws, size_t ws_size,
                              hipStream_t stream) {
  const float* h1 = (const float*)d_in[0];
  const float* h2 = (const float*)d_in[1];
  char* ws = (char*)d_ws;

  __hip_bfloat16* Hb = (__hip_bfloat16*)ws;                       // 4 MB
  float* rowsum      = (float*)(ws + 4194304);                    // 64 KB
  float* posdot      = (float*)(ws + 4194304 + 65536);            // 32 KB
  float* out         = (float*)d_out;

  hipMemsetAsync(ws + 4194304, 0, 65536, stream);                 // zero rowsum
  norm_kernel<<<N_ROWS / 4, 256, 0, stream>>>(h1, h2, Hb, posdot);
  ntx_main<<<dim3(TWO_N / 256, CSPLIT), 256, 0, stream>>>(Hb, rowsum);
  finalize<<<1, 256, 0, stream>>>(rowsum, posdot, out);
}